// Round 7
// baseline (229.564 us; speedup 1.0000x reference)
//
#include <hip/hip_runtime.h>
#include <hip/hip_bf16.h>

typedef __attribute__((ext_vector_type(8))) __bf16 bf16x8;
typedef __attribute__((ext_vector_type(4))) float f32x4;
typedef __attribute__((ext_vector_type(4))) unsigned short u16x4;
typedef unsigned short u16;

#define MFMA16 __builtin_amdgcn_mfma_f32_16x16x32_bf16

#if __has_builtin(__builtin_amdgcn_exp2f)
#define EXP2F __builtin_amdgcn_exp2f
#else
#define EXP2F(x) __expf((x) * 0.69314718056f)
#endif

__device__ inline u16 f32_to_bf16_bits(float f) {
    unsigned u = __builtin_bit_cast(unsigned, f);
    unsigned r = u + 0x7FFFu + ((u >> 16) & 1u);
    return (u16)(r >> 16);
}

__device__ inline void g2l16(const void* g, void* l) {
    __builtin_amdgcn_global_load_lds(
        (const __attribute__((address_space(1))) unsigned int*)g,
        (__attribute__((address_space(3))) unsigned int*)l,
        16, 0, 0);
}

// ---------------- convert: f32 -> bf16 (vectorized) ----------------
__global__ void cvt_bf16_kernel(const float* __restrict__ in, u16* __restrict__ out, int n) {
    int i = (blockIdx.x * 256 + threadIdx.x) * 4;
    if (i >= n) return;
    f32x4 v = *(const f32x4*)&in[i];
    u16x4 r;
#pragma unroll
    for (int j = 0; j < 4; ++j) r[j] = f32_to_bf16_bits(v[j]);
    *(u16x4*)&out[i] = r;
}

// ---------------- convert + transpose: W[K][N] f32 -> WT[N][K] bf16 ----------------
__global__ void cvt_t_kernel(const float* __restrict__ W, u16* __restrict__ WT, int K, int N) {
    int idx = blockIdx.x * 256 + threadIdx.x;
    int k = idx / N;
    int n = idx - k * N;
    WT[(size_t)n * K + k] = f32_to_bf16_bits(W[idx]);
}

// ---------------- GEMM: C[M][N] = A[M][K] * BT[N][K]^T + bias ----------------
// qcols/qscale: columns < qcols get scaled by qscale after bias (pre-scales Q
// by 1/sqrt(d)*log2e so the attention kernel works directly in exp2 domain).
template <int STORE_BF16>
__global__ __launch_bounds__(256) void gemm_nt(
    const u16* __restrict__ A, const u16* __restrict__ BT,
    const float* __restrict__ bias, void* __restrict__ Cv,
    int M, int N, int K, int qcols, float qscale)
{
    __shared__ __align__(16) u16 As[128 * 64];
    __shared__ __align__(16) u16 Bs[128 * 64];
    const int tid = threadIdx.x;
    const int w = tid >> 6, l = tid & 63;
    const int lr = l & 15, lh = l >> 4;
    const int wr = (w >> 1) * 64, wc = (w & 1) * 64;
    const int m0 = blockIdx.y * 128, n0 = blockIdx.x * 128;

    f32x4 acc[4][4];
#pragma unroll
    for (int m = 0; m < 4; ++m)
#pragma unroll
        for (int n = 0; n < 4; ++n) acc[m][n] = (f32x4)(0.0f);

    for (int k0 = 0; k0 < K; k0 += 64) {
        __syncthreads();
#pragma unroll
        for (int p = 0; p < 4; ++p) {
            int f = p * 256 + tid;
            int r = f >> 3, kk = (f & 7) << 3;
            g2l16(A + (size_t)(m0 + r) * K + (k0 + kk), &As[(p * 4 + w) * 512]);
            g2l16(BT + (size_t)(n0 + r) * K + (k0 + kk), &Bs[(p * 4 + w) * 512]);
        }
        __syncthreads();
#pragma unroll
        for (int ks = 0; ks < 2; ++ks) {
            bf16x8 af[4], bfr[4];
#pragma unroll
            for (int m = 0; m < 4; ++m)
                af[m] = *(const bf16x8*)&As[(wr + m * 16 + lr) * 64 + ks * 32 + lh * 8];
#pragma unroll
            for (int n = 0; n < 4; ++n)
                bfr[n] = *(const bf16x8*)&Bs[(wc + n * 16 + lr) * 64 + ks * 32 + lh * 8];
#pragma unroll
            for (int m = 0; m < 4; ++m)
#pragma unroll
                for (int n = 0; n < 4; ++n)
                    acc[m][n] = MFMA16(af[m], bfr[n], acc[m][n], 0, 0, 0);
        }
    }

#pragma unroll
    for (int m = 0; m < 4; ++m) {
        int row = m0 + wr + m * 16 + lh * 4;
#pragma unroll
        for (int n = 0; n < 4; ++n) {
            int col = n0 + wc + n * 16 + lr;
            float bs = bias[col];
            float sc = (col < qcols) ? qscale : 1.0f;
#pragma unroll
            for (int j = 0; j < 4; ++j) {
                float v = (acc[m][n][j] + bs) * sc;
                if (STORE_BF16)
                    ((u16*)Cv)[(size_t)(row + j) * N + col] = f32_to_bf16_bits(v);
                else
                    ((float*)Cv)[(size_t)(row + j) * N + col] = v;
            }
        }
    }
}

// ---------------- causal flash attention v5 ----------------
// QBLK=128 (8 waves x 1 strip of 16 rows), KVBLK=64. Swapped QK^T.
// Triangle pairing over 16 q-tiles (qt, 15-qt) -> uniform 36 steps/block.
// Grid 512 = 2 blocks/CU co-resident (16 waves/CU). K dbuf via global_load_lds
// with per-row XOR swizzle; V reg-staged to swizzled VT. Q pre-scaled (exp2
// domain); masking only on diagonal tiles (uniform branch); defer-max T13.
__global__ __launch_bounds__(512, 2) void attn_kernel(
    const u16* __restrict__ qkv, u16* __restrict__ ctx)
{
    __shared__ __align__(16) u16 SM[24576];   // K dbuf 16KB | V dbuf 16KB | P 8x2KB

    const int bid = blockIdx.x;
    const int xcd = bid & 7, jj = bid >> 3;        // 64 blocks per XCD
    const int bh = xcd * 8 + (jj >> 3);            // 8 heads per XCD (4MB KV = L2)
    const int pr = jj & 7;                         // pair: qt = pr, then 15-pr
    const int b = bh >> 4, h = bh & 15;
    const size_t rowbase = (size_t)b * 2048;
    const int tid = threadIdx.x, w = tid >> 6, l = tid & 63;
    const int lr = l & 15, lh = l >> 4;
    u16* const PL = SM + 16384 + w * 1024;         // [16][64] per wave, (q&7) key

    // staging geometry: wave w stages rows w*8..w*8+7 of the 64-row K/V tile
    const int rstage = w * 8 + (l >> 3);
    const int cstage = l & 7;                       // dest col-chunk
    const int kchunk = cstage ^ (l >> 3);           // inverse-swizzle src (key=row&7)

    bf16x8 vreg;

#pragma unroll
    for (int pass = 0; pass < 2; ++pass) {
        const int qt = pass ? (15 - pr) : pr;
        const int q0 = qt * 128;
        const int nt = 2 * qt + 2;
        const int qbase = q0 + w * 16;

        // Q fragments (MFMA B-operand): lane holds Q[q=qbase+lr][k=lh*8..+7 (+32)]
        const u16* qp = qkv + (rowbase + qbase + lr) * 3072 + h * 64 + lh * 8;
        const bf16x8 qf0 = *(const bf16x8*)qp;
        const bf16x8 qf1 = *(const bf16x8*)(qp + 32);

        f32x4 ot[4];
#pragma unroll
        for (int dt = 0; dt < 4; ++dt) ot[dt] = (f32x4)(0.0f);
        float m_run = -3e38f, l_run = 0.0f;

        // ---- prologue: stage tile 0 (barrier guards SM reuse across passes) ----
        __syncthreads();
        g2l16(qkv + (rowbase + rstage) * 3072 + 1024 + h * 64 + kchunk * 8, SM + w * 512);
        vreg = *(const bf16x8*)(qkv + (rowbase + rstage) * 3072 + 2048 + h * 64 + cstage * 8);
        asm volatile("s_waitcnt vmcnt(0)" ::: "memory");
#pragma unroll
        for (int i = 0; i < 8; ++i) {
            const int d = cstage * 8 + i;
            SM[8192 + (((d * 64 + rstage) ^ (((i ^ cstage) & 7) << 3)))] = ((const u16*)&vreg)[i];
        }
        __syncthreads();

        for (int t = 0; t < nt; ++t) {
            const int c = t & 1;
            const int kb = t * 64;
            u16* const Kb = SM + (c ? 4096 : 0);
            u16* const Vb = SM + 8192 + (c ? 4096 : 0);

            // issue next-tile staging (K -> LDS direct, V -> regs) before compute
            if (t + 1 < nt) {
                const int kb2 = kb + 64;
                g2l16(qkv + (rowbase + kb2 + rstage) * 3072 + 1024 + h * 64 + kchunk * 8,
                      SM + (c ? 0 : 4096) + w * 512);
                vreg = *(const bf16x8*)(qkv + (rowbase + kb2 + rstage) * 3072 + 2048 + h * 64 + cstage * 8);
            }

            if (kb <= qbase + 15) {   // strip visible
                // K A-fragments (swizzled ds_read_b128, key=lr&7)
                bf16x8 kf[4][2];
#pragma unroll
                for (int kt = 0; kt < 4; ++kt)
#pragma unroll
                    for (int ks = 0; ks < 2; ++ks)
                        kf[kt][ks] = *(const bf16x8*)&Kb[((kt * 16 + lr) * 64 + ks * 32 + lh * 8) ^ ((lr & 7) << 3)];

                // S^T[key][q] = K * Q^T : lane owns q = lr (values pre-scaled)
                f32x4 sf[4];
                __builtin_amdgcn_s_setprio(1);
#pragma unroll
                for (int kt = 0; kt < 4; ++kt) {
                    f32x4 z = (f32x4)(0.0f);
                    z = MFMA16(kf[kt][0], qf0, z, 0, 0, 0);
                    z = MFMA16(kf[kt][1], qf1, z, 0, 0, 0);
                    sf[kt] = z;
                }
                __builtin_amdgcn_s_setprio(0);

                float mt = -3e38f;
                if (kb + 63 > qbase) {          // diagonal tile: apply causal mask
                    const int qrow = qbase + lr;
#pragma unroll
                    for (int kt = 0; kt < 4; ++kt)
#pragma unroll
                        for (int j = 0; j < 4; ++j) {
                            float v = sf[kt][j];
                            if (kb + kt * 16 + lh * 4 + j > qrow) v = -3e38f;
                            sf[kt][j] = v;
                            mt = fmaxf(mt, v);
                        }
                } else {                         // full tile: no masking needed
#pragma unroll
                    for (int kt = 0; kt < 4; ++kt)
#pragma unroll
                        for (int j = 0; j < 4; ++j) mt = fmaxf(mt, sf[kt][j]);
                }
                mt = fmaxf(mt, __shfl_xor(mt, 16));
                mt = fmaxf(mt, __shfl_xor(mt, 32));

                // defer-max (T13): skip rescale when max didn't grow by >16
                const bool defer = __all(mt <= m_run + 16.0f);
                float mn = m_run;
                if (!defer) {
                    mn = fmaxf(m_run, mt);
                    const float alpha = EXP2F(m_run - mn);
                    m_run = mn;
                    l_run *= alpha;
#pragma unroll
                    for (int dt = 0; dt < 4; ++dt)
#pragma unroll
                        for (int j = 0; j < 4; ++j) ot[dt][j] *= alpha;
                }
                float rs = 0.0f;
#pragma unroll
                for (int kt = 0; kt < 4; ++kt)
#pragma unroll
                    for (int j = 0; j < 4; ++j) {
                        const float pp = EXP2F(sf[kt][j] - mn);
                        sf[kt][j] = pp;
                        rs += pp;
                    }
                rs += __shfl_xor(rs, 16);
                rs += __shfl_xor(rs, 32);
                l_run += rs;

                // P^T lane-local -> per-wave P_lds [q][key], (q&7) XOR key
#pragma unroll
                for (int kt = 0; kt < 4; ++kt) {
                    u16x4 pk;
#pragma unroll
                    for (int j = 0; j < 4; ++j) pk[j] = f32_to_bf16_bits(sf[kt][j]);
                    *(u16x4*)&PL[(lr * 64 + kt * 16 + lh * 4) ^ ((lr & 7) << 3)] = pk;
                }
                // PV: O^T[d][q] += V^T * P^T
                __builtin_amdgcn_s_setprio(1);
#pragma unroll
                for (int ks = 0; ks < 2; ++ks) {
                    const bf16x8 pb = *(const bf16x8*)&PL[(lr * 64 + ks * 32 + lh * 8) ^ ((lr & 7) << 3)];
#pragma unroll
                    for (int dt = 0; dt < 4; ++dt) {
                        const int vkey = ((lr & 7) ^ (dt * 2 + (lr >> 3))) & 7;
                        const bf16x8 vf = *(const bf16x8*)&Vb[((dt * 16 + lr) * 64 + ks * 32 + lh * 8) ^ (vkey << 3)];
                        ot[dt] = MFMA16(vf, pb, ot[dt], 0, 0, 0);
                    }
                }
                __builtin_amdgcn_s_setprio(0);
            }

            asm volatile("s_waitcnt vmcnt(0)" ::: "memory");
            __syncthreads();
            if (t + 1 < nt) {
                u16* const Vn = SM + 8192 + (c ? 0 : 4096);
#pragma unroll
                for (int i = 0; i < 8; ++i) {
                    const int d = cstage * 8 + i;
                    Vn[((d * 64 + rstage) ^ (((i ^ cstage) & 7) << 3))] = ((const u16*)&vreg)[i];
                }
            }
            __syncthreads();
        }

        // ---- epilogue: O^T -> LDS transpose -> coalesced bf16 stores ----
        __syncthreads();                       // all waves done reading K/V/P
        u16* const out_l = SM + w * 1152;      // [16][72] per wave
        const float inv = 1.0f / l_run;
#pragma unroll
        for (int dt = 0; dt < 4; ++dt)
#pragma unroll
            for (int j = 0; j < 4; ++j)
                out_l[lr * 72 + dt * 16 + lh * 4 + j] = f32_to_bf16_bits(ot[dt][j] * inv);
        __syncthreads();
#pragma unroll
        for (int r4 = 0; r4 < 2; ++r4) {
            const int row = r4 * 8 + (l >> 3);
            const bf16x8 v = *(const bf16x8*)&out_l[row * 72 + (l & 7) * 8];
            *(bf16x8*)(ctx + (rowbase + qbase + row) * 1024 + h * 64 + (l & 7) * 8) = v;
        }
    }
}

extern "C" void kernel_launch(void* const* d_in, const int* in_sizes, int n_in,
                              void* d_out, int out_size, void* d_ws, size_t ws_size,
                              hipStream_t stream) {
    const float* x      = (const float*)d_in[0];
    const float* W_qkv  = (const float*)d_in[1];
    const float* b_qkv  = (const float*)d_in[2];
    const float* W_o    = (const float*)d_in[3];
    const float* b_o    = (const float*)d_in[4];
    float* out = (float*)d_out;

    const int M = 4 * 2048;     // 8192 rows
    const int C = 1024;
    u16* qkv   = (u16*)d_ws;                       // [8192][3072]
    u16* xb    = qkv   + (size_t)M * 3 * C;        // [8192][1024]
    u16* wqkvt = xb    + (size_t)M * C;            // [3072][1024]
    u16* ctx   = wqkvt + (size_t)3 * C * C;        // [8192][1024]
    u16* wot   = ctx   + (size_t)M * C;            // [1024][1024]

    const float SCQ = 0.125f * 1.44269504089f;     // 1/sqrt(64) * log2(e)

    cvt_bf16_kernel<<<(M * C) / (256 * 4), 256, 0, stream>>>(x, xb, M * C);
    cvt_t_kernel<<<(3 * C * C) / 256, 256, 0, stream>>>(W_qkv, wqkvt, C, 3 * C);
    cvt_t_kernel<<<(C * C) / 256, 256, 0, stream>>>(W_o, wot, C, C);

    gemm_nt<1><<<dim3(3 * C / 128, M / 128), 256, 0, stream>>>(xb, wqkvt, b_qkv, qkv, M, 3 * C, C, C, SCQ);

    attn_kernel<<<512, 512, 0, stream>>>(qkv, ctx);

    gemm_nt<0><<<dim3(C / 128, M / 128), 256, 0, stream>>>(ctx, wot, b_o, out, M, C, C, 0, 1.0f);
}

// Round 8
// 211.925 us; speedup vs baseline: 1.0832x; 1.0832x over previous
//
#include <hip/hip_runtime.h>
#include <hip/hip_bf16.h>

typedef __attribute__((ext_vector_type(8))) __bf16 bf16x8;
typedef __attribute__((ext_vector_type(4))) float f32x4;
typedef __attribute__((ext_vector_type(4))) unsigned short u16x4;
typedef __attribute__((ext_vector_type(8))) unsigned short u16x8;
typedef unsigned short u16;

#define MFMA16 __builtin_amdgcn_mfma_f32_16x16x32_bf16

#if __has_builtin(__builtin_amdgcn_exp2f)
#define EXP2F __builtin_amdgcn_exp2f
#else
#define EXP2F(x) __expf((x) * 0.69314718056f)
#endif

__device__ inline u16 f32_to_bf16_bits(float f) {
    unsigned u = __builtin_bit_cast(unsigned, f);
    unsigned r = u + 0x7FFFu + ((u >> 16) & 1u);
    return (u16)(r >> 16);
}

__device__ inline void g2l16(const void* g, void* l) {
    __builtin_amdgcn_global_load_lds(
        (const __attribute__((address_space(1))) unsigned int*)g,
        (__attribute__((address_space(3))) unsigned int*)l,
        16, 0, 0);
}

// ---------------- convert: f32 -> bf16 (vectorized) ----------------
__global__ void cvt_bf16_kernel(const float* __restrict__ in, u16* __restrict__ out, int n) {
    int i = (blockIdx.x * 256 + threadIdx.x) * 4;
    if (i >= n) return;
    f32x4 v = *(const f32x4*)&in[i];
    u16x4 r;
#pragma unroll
    for (int j = 0; j < 4; ++j) r[j] = f32_to_bf16_bits(v[j]);
    *(u16x4*)&out[i] = r;
}

// ---------------- transpose+convert: W[K][N] f32 -> WT[N][K] bf16 ----------------
// lane l <-> output row n: reads coalesced (wave reads 256B of one W row per k),
// writes 16B/lane; the 4 waves of a block fill complete 64B lines in L2.
__global__ __launch_bounds__(256) void cvt_t_kernel(const float* __restrict__ W,
                                                    u16* __restrict__ WT, int K, int N) {
    const int w = threadIdx.x >> 6, l = threadIdx.x & 63;
    const int n = blockIdx.x * 64 + l;
    const int k0 = blockIdx.y * 32 + w * 8;
    u16x8 r;
#pragma unroll
    for (int i = 0; i < 8; ++i)
        r[i] = f32_to_bf16_bits(W[(size_t)(k0 + i) * N + n]);
    *(u16x8*)&WT[(size_t)n * K + k0] = r;
}

// ---------------- GEMM: C[M][N] = A[M][K] * BT[N][K]^T + bias ----------------
// qcols/qscale: columns < qcols scaled by qscale after bias (pre-scale Q into
// exp2 domain for the attention kernel).
template <int STORE_BF16>
__global__ __launch_bounds__(256) void gemm_nt(
    const u16* __restrict__ A, const u16* __restrict__ BT,
    const float* __restrict__ bias, void* __restrict__ Cv,
    int M, int N, int K, int qcols, float qscale)
{
    __shared__ __align__(16) u16 As[128 * 64];
    __shared__ __align__(16) u16 Bs[128 * 64];
    const int tid = threadIdx.x;
    const int w = tid >> 6, l = tid & 63;
    const int lr = l & 15, lh = l >> 4;
    const int wr = (w >> 1) * 64, wc = (w & 1) * 64;
    const int m0 = blockIdx.y * 128, n0 = blockIdx.x * 128;

    f32x4 acc[4][4];
#pragma unroll
    for (int m = 0; m < 4; ++m)
#pragma unroll
        for (int n = 0; n < 4; ++n) acc[m][n] = (f32x4)(0.0f);

    for (int k0 = 0; k0 < K; k0 += 64) {
        __syncthreads();
#pragma unroll
        for (int p = 0; p < 4; ++p) {
            int f = p * 256 + tid;
            int r = f >> 3, kk = (f & 7) << 3;
            g2l16(A + (size_t)(m0 + r) * K + (k0 + kk), &As[(p * 4 + w) * 512]);
            g2l16(BT + (size_t)(n0 + r) * K + (k0 + kk), &Bs[(p * 4 + w) * 512]);
        }
        __syncthreads();
#pragma unroll
        for (int ks = 0; ks < 2; ++ks) {
            bf16x8 af[4], bfr[4];
#pragma unroll
            for (int m = 0; m < 4; ++m)
                af[m] = *(const bf16x8*)&As[(wr + m * 16 + lr) * 64 + ks * 32 + lh * 8];
#pragma unroll
            for (int n = 0; n < 4; ++n)
                bfr[n] = *(const bf16x8*)&Bs[(wc + n * 16 + lr) * 64 + ks * 32 + lh * 8];
#pragma unroll
            for (int m = 0; m < 4; ++m)
#pragma unroll
                for (int n = 0; n < 4; ++n)
                    acc[m][n] = MFMA16(af[m], bfr[n], acc[m][n], 0, 0, 0);
        }
    }

#pragma unroll
    for (int m = 0; m < 4; ++m) {
        int row = m0 + wr + m * 16 + lh * 4;
#pragma unroll
        for (int n = 0; n < 4; ++n) {
            int col = n0 + wc + n * 16 + lr;
            float bs = bias[col];
            float sc = (col < qcols) ? qscale : 1.0f;
#pragma unroll
            for (int j = 0; j < 4; ++j) {
                float v = (acc[m][n][j] + bs) * sc;
                if (STORE_BF16)
                    ((u16*)Cv)[(size_t)(row + j) * N + col] = f32_to_bf16_bits(v);
                else
                    ((float*)Cv)[(size_t)(row + j) * N + col] = v;
            }
        }
    }
}

// ---------------- causal flash attention v6 ----------------
// QBLK=128 (8 waves x 16-row strip), KVBLK=64, swapped QK^T, triangle pairing
// (qt, 15-qt) -> uniform 36 steps. SINGLE barrier per tile-step: stage K(t+1)
// (global_load_lds) + V(t+1)->reg at step start; after compute vmcnt(0) (hidden
// by compute), write V^T(t+1) to the idle buffer, one __syncthreads.
__global__ __launch_bounds__(512, 2) void attn_kernel(
    const u16* __restrict__ qkv, u16* __restrict__ ctx)
{
    __shared__ __align__(16) u16 SM[24576];   // K dbuf 16KB | V dbuf 16KB | P 8x2KB

    const int bid = blockIdx.x;
    const int xcd = bid & 7, jj = bid >> 3;        // 64 blocks per XCD
    const int bh = xcd * 8 + (jj >> 3);            // 8 heads per XCD (4MB KV = L2)
    const int pr = jj & 7;                         // pair: qt = pr, then 15-pr
    const int b = bh >> 4, h = bh & 15;
    const size_t rowbase = (size_t)b * 2048;
    const int tid = threadIdx.x, w = tid >> 6, l = tid & 63;
    const int lr = l & 15, lh = l >> 4;
    u16* const PL = SM + 16384 + w * 1024;         // [16][64] per wave, (q&7) key

    // staging geometry: wave w stages rows w*8..w*8+7 of the 64-row K/V tile
    const int rstage = w * 8 + (l >> 3);
    const int cstage = l & 7;                       // dest col-chunk
    const int kchunk = cstage ^ (l >> 3);           // inverse-swizzle src (key=row&7)

    bf16x8 vreg;

#pragma unroll
    for (int pass = 0; pass < 2; ++pass) {
        const int qt = pass ? (15 - pr) : pr;
        const int q0 = qt * 128;
        const int nt = 2 * qt + 2;
        const int qbase = q0 + w * 16;

        // Q fragments (MFMA B-operand): lane holds Q[q=qbase+lr][k=lh*8..+7 (+32)]
        const u16* qp = qkv + (rowbase + qbase + lr) * 3072 + h * 64 + lh * 8;
        const bf16x8 qf0 = *(const bf16x8*)qp;
        const bf16x8 qf1 = *(const bf16x8*)(qp + 32);

        f32x4 ot[4];
#pragma unroll
        for (int dt = 0; dt < 4; ++dt) ot[dt] = (f32x4)(0.0f);
        float m_run = -3e38f, l_run = 0.0f;

        // ---- prologue: stage tile 0 (barrier guards SM reuse across passes) ----
        __syncthreads();
        g2l16(qkv + (rowbase + rstage) * 3072 + 1024 + h * 64 + kchunk * 8, SM + w * 512);
        vreg = *(const bf16x8*)(qkv + (rowbase + rstage) * 3072 + 2048 + h * 64 + cstage * 8);
        asm volatile("s_waitcnt vmcnt(0)" ::: "memory");
#pragma unroll
        for (int i = 0; i < 8; ++i) {
            const int d = cstage * 8 + i;
            SM[8192 + (((d * 64 + rstage) ^ (((i ^ cstage) & 7) << 3)))] = ((const u16*)&vreg)[i];
        }
        __syncthreads();

        for (int t = 0; t < nt; ++t) {
            const int c = t & 1;
            const int kb = t * 64;
            u16* const Kb = SM + (c ? 4096 : 0);
            u16* const Vb = SM + 8192 + (c ? 4096 : 0);

            // issue next-tile staging first (K -> LDS direct, V -> regs)
            if (t + 1 < nt) {
                const int kb2 = kb + 64;
                g2l16(qkv + (rowbase + kb2 + rstage) * 3072 + 1024 + h * 64 + kchunk * 8,
                      SM + (c ? 0 : 4096) + w * 512);
                vreg = *(const bf16x8*)(qkv + (rowbase + kb2 + rstage) * 3072 + 2048 + h * 64 + cstage * 8);
            }

            if (kb <= qbase + 15) {   // strip visible
                // K A-fragments (swizzled ds_read_b128, key=lr&7)
                bf16x8 kf[4][2];
#pragma unroll
                for (int kt = 0; kt < 4; ++kt)
#pragma unroll
                    for (int ks = 0; ks < 2; ++ks)
                        kf[kt][ks] = *(const bf16x8*)&Kb[((kt * 16 + lr) * 64 + ks * 32 + lh * 8) ^ ((lr & 7) << 3)];

                // S^T[key][q] = K * Q^T : lane owns q = lr (values pre-scaled)
                f32x4 sf[4];
                __builtin_amdgcn_s_setprio(1);
#pragma unroll
                for (int kt = 0; kt < 4; ++kt) {
                    f32x4 z = (f32x4)(0.0f);
                    z = MFMA16(kf[kt][0], qf0, z, 0, 0, 0);
                    z = MFMA16(kf[kt][1], qf1, z, 0, 0, 0);
                    sf[kt] = z;
                }
                __builtin_amdgcn_s_setprio(0);

                float mt = -3e38f;
                if (kb + 63 > qbase) {          // diagonal tile: apply causal mask
                    const int qrow = qbase + lr;
#pragma unroll
                    for (int kt = 0; kt < 4; ++kt)
#pragma unroll
                        for (int j = 0; j < 4; ++j) {
                            float v = sf[kt][j];
                            if (kb + kt * 16 + lh * 4 + j > qrow) v = -3e38f;
                            sf[kt][j] = v;
                            mt = fmaxf(mt, v);
                        }
                } else {                         // full tile: no masking needed
#pragma unroll
                    for (int kt = 0; kt < 4; ++kt)
#pragma unroll
                        for (int j = 0; j < 4; ++j) mt = fmaxf(mt, sf[kt][j]);
                }
                mt = fmaxf(mt, __shfl_xor(mt, 16));
                mt = fmaxf(mt, __shfl_xor(mt, 32));

                // defer-max (T13): skip rescale when max didn't grow by >16
                const bool defer = __all(mt <= m_run + 16.0f);
                float mn = m_run;
                if (!defer) {
                    mn = fmaxf(m_run, mt);
                    const float alpha = EXP2F(m_run - mn);
                    m_run = mn;
                    l_run *= alpha;
#pragma unroll
                    for (int dt = 0; dt < 4; ++dt)
#pragma unroll
                        for (int j = 0; j < 4; ++j) ot[dt][j] *= alpha;
                }
                float rs = 0.0f;
#pragma unroll
                for (int kt = 0; kt < 4; ++kt)
#pragma unroll
                    for (int j = 0; j < 4; ++j) {
                        const float pp = EXP2F(sf[kt][j] - mn);
                        sf[kt][j] = pp;
                        rs += pp;
                    }
                rs += __shfl_xor(rs, 16);
                rs += __shfl_xor(rs, 32);
                l_run += rs;

                // P^T lane-local -> per-wave P_lds [q][key], (q&7) XOR key
#pragma unroll
                for (int kt = 0; kt < 4; ++kt) {
                    u16x4 pk;
#pragma unroll
                    for (int j = 0; j < 4; ++j) pk[j] = f32_to_bf16_bits(sf[kt][j]);
                    *(u16x4*)&PL[(lr * 64 + kt * 16 + lh * 4) ^ ((lr & 7) << 3)] = pk;
                }
                // PV: O^T[d][q] += V^T * P^T
                __builtin_amdgcn_s_setprio(1);
#pragma unroll
                for (int ks = 0; ks < 2; ++ks) {
                    const bf16x8 pb = *(const bf16x8*)&PL[(lr * 64 + ks * 32 + lh * 8) ^ ((lr & 7) << 3)];
#pragma unroll
                    for (int dt = 0; dt < 4; ++dt) {
                        const int vkey = ((lr & 7) ^ (dt * 2 + (lr >> 3))) & 7;
                        const bf16x8 vf = *(const bf16x8*)&Vb[((dt * 16 + lr) * 64 + ks * 32 + lh * 8) ^ (vkey << 3)];
                        ot[dt] = MFMA16(vf, pb, ot[dt], 0, 0, 0);
                    }
                }
                __builtin_amdgcn_s_setprio(0);
            }

            // K(t+1)/V(t+1) have had the whole compute to land
            asm volatile("s_waitcnt vmcnt(0)" ::: "memory");
            if (t + 1 < nt) {
                u16* const Vn = SM + 8192 + (c ? 0 : 4096);
#pragma unroll
                for (int i = 0; i < 8; ++i) {
                    const int d = cstage * 8 + i;
                    Vn[((d * 64 + rstage) ^ (((i ^ cstage) & 7) << 3))] = ((const u16*)&vreg)[i];
                }
            }
            __syncthreads();   // single barrier per tile-step
        }

        // ---- epilogue: O^T -> LDS transpose -> coalesced bf16 stores ----
        u16* const out_l = SM + w * 1152;      // [16][72] per wave (private)
        const float inv = 1.0f / l_run;
#pragma unroll
        for (int dt = 0; dt < 4; ++dt)
#pragma unroll
            for (int j = 0; j < 4; ++j)
                out_l[lr * 72 + dt * 16 + lh * 4 + j] = f32_to_bf16_bits(ot[dt][j] * inv);
#pragma unroll
        for (int r4 = 0; r4 < 2; ++r4) {
            const int row = r4 * 8 + (l >> 3);
            const bf16x8 v = *(const bf16x8*)&out_l[row * 72 + (l & 7) * 8];
            *(bf16x8*)(ctx + (rowbase + qbase + row) * 1024 + h * 64 + (l & 7) * 8) = v;
        }
    }
}

extern "C" void kernel_launch(void* const* d_in, const int* in_sizes, int n_in,
                              void* d_out, int out_size, void* d_ws, size_t ws_size,
                              hipStream_t stream) {
    const float* x      = (const float*)d_in[0];
    const float* W_qkv  = (const float*)d_in[1];
    const float* b_qkv  = (const float*)d_in[2];
    const float* W_o    = (const float*)d_in[3];
    const float* b_o    = (const float*)d_in[4];
    float* out = (float*)d_out;

    const int M = 4 * 2048;     // 8192 rows
    const int C = 1024;
    u16* qkv   = (u16*)d_ws;                       // [8192][3072]
    u16* xb    = qkv   + (size_t)M * 3 * C;        // [8192][1024]
    u16* wqkvt = xb    + (size_t)M * C;            // [3072][1024]
    u16* ctx   = wqkvt + (size_t)3 * C * C;        // [8192][1024]
    u16* wot   = ctx   + (size_t)M * C;            // [1024][1024]

    const float SCQ = 0.125f * 1.44269504089f;     // 1/sqrt(64) * log2(e)

    cvt_bf16_kernel<<<(M * C) / (256 * 4), 256, 0, stream>>>(x, xb, M * C);
    cvt_t_kernel<<<dim3(3 * C / 64, C / 32), 256, 0, stream>>>(W_qkv, wqkvt, C, 3 * C);
    cvt_t_kernel<<<dim3(C / 64, C / 32), 256, 0, stream>>>(W_o, wot, C, C);

    gemm_nt<1><<<dim3(3 * C / 128, M / 128), 256, 0, stream>>>(xb, wqkvt, b_qkv, qkv, M, 3 * C, C, C, SCQ);

    attn_kernel<<<512, 512, 0, stream>>>(qkv, ctx);

    gemm_nt<0><<<dim3(C / 128, M / 128), 256, 0, stream>>>(ctx, wot, b_o, out, M, C, C, 0, 1.0f);
}

// Round 9
// 190.197 us; speedup vs baseline: 1.2070x; 1.1142x over previous
//
#include <hip/hip_runtime.h>
#include <hip/hip_bf16.h>

typedef __attribute__((ext_vector_type(8))) __bf16 bf16x8;
typedef __attribute__((ext_vector_type(4))) float f32x4;
typedef __attribute__((ext_vector_type(16))) float f32x16;
typedef __attribute__((ext_vector_type(4))) unsigned short u16x4;
typedef __attribute__((ext_vector_type(8))) unsigned short u16x8;
typedef unsigned short u16;

#define MFMA16 __builtin_amdgcn_mfma_f32_16x16x32_bf16
#define MFMA32 __builtin_amdgcn_mfma_f32_32x32x16_bf16

#if __has_builtin(__builtin_amdgcn_exp2f)
#define EXP2F __builtin_amdgcn_exp2f
#else
#define EXP2F(x) __expf((x) * 0.69314718056f)
#endif

__device__ inline u16 f32_to_bf16_bits(float f) {      // RNE (weights/outputs)
    unsigned u = __builtin_bit_cast(unsigned, f);
    unsigned r = u + 0x7FFFu + ((u >> 16) & 1u);
    return (u16)(r >> 16);
}
__device__ inline u16 f32_to_bf16_fast(float f) {      // round-half-up (P only)
    unsigned u = __builtin_bit_cast(unsigned, f);
    return (u16)((u + 0x8000u) >> 16);
}

__device__ inline void g2l16(const void* g, void* l) {
    __builtin_amdgcn_global_load_lds(
        (const __attribute__((address_space(1))) unsigned int*)g,
        (__attribute__((address_space(3))) unsigned int*)l,
        16, 0, 0);
}

// ---------------- convert: f32 -> bf16 (vectorized) ----------------
__global__ void cvt_bf16_kernel(const float* __restrict__ in, u16* __restrict__ out, int n) {
    int i = (blockIdx.x * 256 + threadIdx.x) * 4;
    if (i >= n) return;
    f32x4 v = *(const f32x4*)&in[i];
    u16x4 r;
#pragma unroll
    for (int j = 0; j < 4; ++j) r[j] = f32_to_bf16_bits(v[j]);
    *(u16x4*)&out[i] = r;
}

// ---------------- transpose+convert: W[K][N] f32 -> WT[N][K] bf16 ----------------
__global__ __launch_bounds__(256) void cvt_t_kernel(const float* __restrict__ W,
                                                    u16* __restrict__ WT, int K, int N) {
    const int w = threadIdx.x >> 6, l = threadIdx.x & 63;
    const int n = blockIdx.x * 64 + l;
    const int k0 = blockIdx.y * 32 + w * 8;
    u16x8 r;
#pragma unroll
    for (int i = 0; i < 8; ++i)
        r[i] = f32_to_bf16_bits(W[(size_t)(k0 + i) * N + n]);
    *(u16x8*)&WT[(size_t)n * K + k0] = r;
}

// ---------------- GEMM: C[M][N] = A[M][K] * BT[N][K]^T + bias ----------------
template <int STORE_BF16>
__global__ __launch_bounds__(256) void gemm_nt(
    const u16* __restrict__ A, const u16* __restrict__ BT,
    const float* __restrict__ bias, void* __restrict__ Cv,
    int M, int N, int K, int qcols, float qscale)
{
    __shared__ __align__(16) u16 As[128 * 64];
    __shared__ __align__(16) u16 Bs[128 * 64];
    const int tid = threadIdx.x;
    const int w = tid >> 6, l = tid & 63;
    const int lr = l & 15, lh = l >> 4;
    const int wr = (w >> 1) * 64, wc = (w & 1) * 64;
    const int m0 = blockIdx.y * 128, n0 = blockIdx.x * 128;

    f32x4 acc[4][4];
#pragma unroll
    for (int m = 0; m < 4; ++m)
#pragma unroll
        for (int n = 0; n < 4; ++n) acc[m][n] = (f32x4)(0.0f);

    for (int k0 = 0; k0 < K; k0 += 64) {
        __syncthreads();
#pragma unroll
        for (int p = 0; p < 4; ++p) {
            int f = p * 256 + tid;
            int r = f >> 3, kk = (f & 7) << 3;
            g2l16(A + (size_t)(m0 + r) * K + (k0 + kk), &As[(p * 4 + w) * 512]);
            g2l16(BT + (size_t)(n0 + r) * K + (k0 + kk), &Bs[(p * 4 + w) * 512]);
        }
        __syncthreads();
#pragma unroll
        for (int ks = 0; ks < 2; ++ks) {
            bf16x8 af[4], bfr[4];
#pragma unroll
            for (int m = 0; m < 4; ++m)
                af[m] = *(const bf16x8*)&As[(wr + m * 16 + lr) * 64 + ks * 32 + lh * 8];
#pragma unroll
            for (int n = 0; n < 4; ++n)
                bfr[n] = *(const bf16x8*)&Bs[(wc + n * 16 + lr) * 64 + ks * 32 + lh * 8];
#pragma unroll
            for (int m = 0; m < 4; ++m)
#pragma unroll
                for (int n = 0; n < 4; ++n)
                    acc[m][n] = MFMA16(af[m], bfr[n], acc[m][n], 0, 0, 0);
        }
    }

#pragma unroll
    for (int m = 0; m < 4; ++m) {
        int row = m0 + wr + m * 16 + lh * 4;
#pragma unroll
        for (int n = 0; n < 4; ++n) {
            int col = n0 + wc + n * 16 + lr;
            float bs = bias[col];
            float sc = (col < qcols) ? qscale : 1.0f;
#pragma unroll
            for (int j = 0; j < 4; ++j) {
                float v = (acc[m][n][j] + bs) * sc;
                if (STORE_BF16)
                    ((u16*)Cv)[(size_t)(row + j) * N + col] = f32_to_bf16_bits(v);
                else
                    ((float*)Cv)[(size_t)(row + j) * N + col] = v;
            }
        }
    }
}

// ---------------- causal flash attention v7: 32x32 MFMA ----------------
// QBLK=256 (8 waves x 32-row strip), KVBLK=64, swapped QK^T (S^T = K*Q^T) via
// mfma_32x32x16. Lane owns q=lane&31 (16 S-rows split lane<32/lane>=32):
// softmax = in-lane tree + ONE shfl_xor(32). Triangle pairing (qt,7-qt) ->
// uniform 36 steps, grid 256. K dbuf via global_load_lds + row&7 XOR swizzle;
// V reg-staged to swizzled VT; P via per-wave [32][64] swizzled LDS.
__global__ __launch_bounds__(512, 2) void attn_kernel(
    const u16* __restrict__ qkv, u16* __restrict__ ctx)
{
    __shared__ __align__(16) u16 SM[32768];  // K 2x8KB | V 2x8KB | P 8x4KB

    const int bid = blockIdx.x;
    const int xcd = bid & 7, jj = bid >> 3;        // 32 blocks per XCD
    const int bh = xcd * 8 + (jj >> 2);            // 8 heads per XCD (4MB KV = L2)
    const int pr = jj & 3;                         // pair: qt = pr, then 7-pr
    const int b = bh >> 4, h = bh & 15;
    const size_t rowbase = (size_t)b * 2048;
    const int tid = threadIdx.x, w = tid >> 6, l = tid & 63;
    const int lq = l & 31, lk = l >> 5;            // q-col owner, k-half
    u16* const PL = SM + 16384 + w * 2048;         // [32][64] per wave, (q&7) key

    // staging geometry: wave w stages rows w*8..w*8+7 of the 64-row K/V tile
    const int rstage = w * 8 + (l >> 3);
    const int cstage = l & 7;
    const int kchunk = cstage ^ (l >> 3);          // inverse-swizzle src (key=row&7)

    bf16x8 vreg;

#pragma unroll
    for (int pass = 0; pass < 2; ++pass) {
        const int qt = pass ? (7 - pr) : pr;
        const int q0 = qt * 256;
        const int nt = 4 * qt + 4;
        const int qbase = q0 + w * 32;

        // Q B-frags: lane holds Q[q=qbase+lq][k=j*16+lk*8 .. +7]
        const u16* qp = qkv + (rowbase + qbase + lq) * 3072 + h * 64 + lk * 8;
        bf16x8 qf[4];
#pragma unroll
        for (int j = 0; j < 4; ++j) qf[j] = *(const bf16x8*)(qp + j * 16);

        f32x16 ot[2];
#pragma unroll
        for (int dt = 0; dt < 2; ++dt) ot[dt] = (f32x16)(0.0f);
        float m_run = -3e38f, l_run = 0.0f;

        // ---- prologue: stage tile 0 ----
        __syncthreads();
        g2l16(qkv + (rowbase + rstage) * 3072 + 1024 + h * 64 + kchunk * 8, SM + w * 512);
        vreg = *(const bf16x8*)(qkv + (rowbase + rstage) * 3072 + 2048 + h * 64 + cstage * 8);
        asm volatile("s_waitcnt vmcnt(0)" ::: "memory");
#pragma unroll
        for (int i = 0; i < 8; ++i) {
            const int d = cstage * 8 + i;
            SM[8192 + (((d * 64 + rstage) ^ (((i ^ cstage) & 7) << 3)))] = ((const u16*)&vreg)[i];
        }
        __syncthreads();

        for (int t = 0; t < nt; ++t) {
            const int c = t & 1;
            const int kb = t * 64;
            u16* const Kb = SM + (c ? 4096 : 0);
            u16* const Vb = SM + 8192 + (c ? 4096 : 0);

            if (t + 1 < nt) {   // issue next-tile staging first
                const int kb2 = kb + 64;
                g2l16(qkv + (rowbase + kb2 + rstage) * 3072 + 1024 + h * 64 + kchunk * 8,
                      SM + (c ? 0 : 4096) + w * 512);
                vreg = *(const bf16x8*)(qkv + (rowbase + kb2 + rstage) * 3072 + 2048 + h * 64 + cstage * 8);
            }

            if (kb <= qbase + 31) {   // strip visible
                // K A-frags: K[kt*32+lq][j*16+lk*8..+7], swizzled (key=row&7=lq&7)
                bf16x8 kf[2][4];
#pragma unroll
                for (int kt = 0; kt < 2; ++kt)
#pragma unroll
                    for (int j = 0; j < 4; ++j)
                        kf[kt][j] = *(const bf16x8*)&Kb[((kt * 32 + lq) * 64 + j * 16 + lk * 8) ^ ((lq & 7) << 3)];

                // S^T[key][q]: 2 blocks of 32 keys, chained K=16 MFMAs
                f32x16 sf[2];
                __builtin_amdgcn_s_setprio(1);
#pragma unroll
                for (int kt = 0; kt < 2; ++kt) {
                    f32x16 z = (f32x16)(0.0f);
#pragma unroll
                    for (int j = 0; j < 4; ++j) z = MFMA32(kf[kt][j], qf[j], z, 0, 0, 0);
                    sf[kt] = z;
                }
                __builtin_amdgcn_s_setprio(0);

                // causal mask on diagonal tiles; in-lane max over 32 elems
                float mt = -3e38f;
                if (kb + 63 > qbase) {
                    const int qrow = qbase + lq;
#pragma unroll
                    for (int kt = 0; kt < 2; ++kt)
#pragma unroll
                        for (int r = 0; r < 16; ++r) {
                            const int key = kb + kt * 32 + (r & 3) + 8 * (r >> 2) + 4 * lk;
                            float v = sf[kt][r];
                            if (key > qrow) v = -3e38f;
                            sf[kt][r] = v;
                            mt = fmaxf(mt, v);
                        }
                } else {
#pragma unroll
                    for (int kt = 0; kt < 2; ++kt)
#pragma unroll
                        for (int r = 0; r < 16; ++r) mt = fmaxf(mt, sf[kt][r]);
                }
                mt = fmaxf(mt, __shfl_xor(mt, 32));   // q-col split across lane/lane+32

                // defer-max (T13)
                const bool defer = __all(mt <= m_run + 16.0f);
                float mn = m_run;
                if (!defer) {
                    mn = fmaxf(m_run, mt);
                    const float alpha = EXP2F(m_run - mn);
                    m_run = mn;
                    l_run *= alpha;
#pragma unroll
                    for (int dt = 0; dt < 2; ++dt)
#pragma unroll
                        for (int r = 0; r < 16; ++r) ot[dt][r] *= alpha;
                }
                float rs = 0.0f;
#pragma unroll
                for (int kt = 0; kt < 2; ++kt)
#pragma unroll
                    for (int r = 0; r < 16; ++r) {
                        const float pp = EXP2F(sf[kt][r] - mn);
                        sf[kt][r] = pp;
                        rs += pp;
                    }
                rs += __shfl_xor(rs, 32);
                l_run += rs;

                // P -> PL[q][key] (reg-group of 4 = consecutive keys -> b64)
#pragma unroll
                for (int kt = 0; kt < 2; ++kt)
#pragma unroll
                    for (int rg = 0; rg < 4; ++rg) {
                        u16x4 pk;
#pragma unroll
                        for (int j2 = 0; j2 < 4; ++j2) pk[j2] = f32_to_bf16_fast(sf[kt][rg * 4 + j2]);
                        *(u16x4*)&PL[((lq * 64) + (kt * 32 + rg * 8 + lk * 4)) ^ ((lq & 7) << 3)] = pk;
                    }

                // PV: O^T[d][q] += V^T * P  (A=V^T frag, B=P frag)
                __builtin_amdgcn_s_setprio(1);
#pragma unroll
                for (int k0 = 0; k0 < 4; ++k0) {
                    const bf16x8 pb = *(const bf16x8*)&PL[((lq * 64) + (k0 * 16 + lk * 8)) ^ ((lq & 7) << 3)];
#pragma unroll
                    for (int dt = 0; dt < 2; ++dt) {
                        const int d = dt * 32 + lq;
                        const int vswz = ((d & 7) ^ (d >> 3)) & 7;
                        const bf16x8 vf = *(const bf16x8*)&Vb[((d * 64) + (k0 * 16 + lk * 8)) ^ (vswz << 3)];
                        ot[dt] = MFMA32(vf, pb, ot[dt], 0, 0, 0);
                    }
                }
                __builtin_amdgcn_s_setprio(0);
            }

            asm volatile("s_waitcnt vmcnt(0)" ::: "memory");
            if (t + 1 < nt) {
                u16* const Vn = SM + 8192 + (c ? 0 : 4096);
#pragma unroll
                for (int i = 0; i < 8; ++i) {
                    const int d = cstage * 8 + i;
                    Vn[((d * 64 + rstage) ^ (((i ^ cstage) & 7) << 3))] = ((const u16*)&vreg)[i];
                }
            }
            __syncthreads();   // single barrier per tile-step
        }

        // ---- epilogue: O^T -> LDS transpose -> coalesced bf16 stores ----
        u16* const out_l = SM + w * 2176;   // [32][68] per wave
        const float inv = 1.0f / l_run;
#pragma unroll
        for (int dt = 0; dt < 2; ++dt)
#pragma unroll
            for (int r = 0; r < 16; ++r) {
                const int d = dt * 32 + (r & 3) + 8 * (r >> 2) + 4 * lk;
                out_l[lq * 68 + d] = f32_to_bf16_bits(ot[dt][r] * inv);
            }
#pragma unroll
        for (int rr = 0; rr < 4; ++rr) {
            const int row = rr * 8 + (l >> 3);
            const bf16x8 v = *(const bf16x8*)&out_l[row * 68 + (l & 7) * 8];
            *(bf16x8*)(ctx + (rowbase + qbase + row) * 1024 + h * 64 + (l & 7) * 8) = v;
        }
    }
}

extern "C" void kernel_launch(void* const* d_in, const int* in_sizes, int n_in,
                              void* d_out, int out_size, void* d_ws, size_t ws_size,
                              hipStream_t stream) {
    const float* x      = (const float*)d_in[0];
    const float* W_qkv  = (const float*)d_in[1];
    const float* b_qkv  = (const float*)d_in[2];
    const float* W_o    = (const float*)d_in[3];
    const float* b_o    = (const float*)d_in[4];
    float* out = (float*)d_out;

    const int M = 4 * 2048;     // 8192 rows
    const int C = 1024;
    u16* qkv   = (u16*)d_ws;                       // [8192][3072]
    u16* xb    = qkv   + (size_t)M * 3 * C;        // [8192][1024]
    u16* wqkvt = xb    + (size_t)M * C;            // [3072][1024]
    u16* ctx   = wqkvt + (size_t)3 * C * C;        // [8192][1024]
    u16* wot   = ctx   + (size_t)M * C;            // [1024][1024]

    const float SCQ = 0.125f * 1.44269504089f;     // 1/sqrt(64) * log2(e)

    cvt_bf16_kernel<<<(M * C) / (256 * 4), 256, 0, stream>>>(x, xb, M * C);
    cvt_t_kernel<<<dim3(3 * C / 64, C / 32), 256, 0, stream>>>(W_qkv, wqkvt, C, 3 * C);
    cvt_t_kernel<<<dim3(C / 64, C / 32), 256, 0, stream>>>(W_o, wot, C, C);

    gemm_nt<1><<<dim3(3 * C / 128, M / 128), 256, 0, stream>>>(xb, wqkvt, b_qkv, qkv, M, 3 * C, C, C, SCQ);

    attn_kernel<<<256, 512, 0, stream>>>(qkv, ctx);

    gemm_nt<0><<<dim3(C / 128, M / 128), 256, 0, stream>>>(ctx, wot, b_o, out, M, C, C, 0, 1.0f);
}

// Round 10
// 175.710 us; speedup vs baseline: 1.3065x; 1.0825x over previous
//
#include <hip/hip_runtime.h>
#include <hip/hip_bf16.h>

typedef __attribute__((ext_vector_type(8))) __bf16 bf16x8;
typedef __attribute__((ext_vector_type(4))) float f32x4;
typedef __attribute__((ext_vector_type(16))) float f32x16;
typedef __attribute__((ext_vector_type(4))) unsigned short u16x4;
typedef __attribute__((ext_vector_type(8))) unsigned short u16x8;
typedef unsigned short u16;

#define MFMA16 __builtin_amdgcn_mfma_f32_16x16x32_bf16
#define MFMA32 __builtin_amdgcn_mfma_f32_32x32x16_bf16

#if __has_builtin(__builtin_amdgcn_exp2f)
#define EXP2F __builtin_amdgcn_exp2f
#else
#define EXP2F(x) __expf((x) * 0.69314718056f)
#endif

__device__ inline u16 f32_to_bf16_bits(float f) {      // RNE (weights/outputs)
    unsigned u = __builtin_bit_cast(unsigned, f);
    unsigned r = u + 0x7FFFu + ((u >> 16) & 1u);
    return (u16)(r >> 16);
}
__device__ inline u16 f32_to_bf16_fast(float f) {      // round-half-up (P only)
    unsigned u = __builtin_bit_cast(unsigned, f);
    return (u16)((u + 0x8000u) >> 16);
}

__device__ inline void g2l16(const void* g, void* l) {
    __builtin_amdgcn_global_load_lds(
        (const __attribute__((address_space(1))) unsigned int*)g,
        (__attribute__((address_space(3))) unsigned int*)l,
        16, 0, 0);
}

// ---------------- convert: f32 -> bf16 (vectorized) ----------------
__global__ void cvt_bf16_kernel(const float* __restrict__ in, u16* __restrict__ out, int n) {
    int i = (blockIdx.x * 256 + threadIdx.x) * 4;
    if (i >= n) return;
    f32x4 v = *(const f32x4*)&in[i];
    u16x4 r;
#pragma unroll
    for (int j = 0; j < 4; ++j) r[j] = f32_to_bf16_bits(v[j]);
    *(u16x4*)&out[i] = r;
}

// ---------------- transpose+convert: W[K][N] f32 -> WT[N][K] bf16 ----------------
__global__ __launch_bounds__(256) void cvt_t_kernel(const float* __restrict__ W,
                                                    u16* __restrict__ WT, int K, int N) {
    const int w = threadIdx.x >> 6, l = threadIdx.x & 63;
    const int n = blockIdx.x * 64 + l;
    const int k0 = blockIdx.y * 32 + w * 8;
    u16x8 r;
#pragma unroll
    for (int i = 0; i < 8; ++i)
        r[i] = f32_to_bf16_bits(W[(size_t)(k0 + i) * N + n]);
    *(u16x8*)&WT[(size_t)n * K + k0] = r;
}

// ---------------- GEMM v2: C[M][N] = A[M][K] * BT[N][K]^T + bias ----------------
// 128x128 tile, BK=32, 4 waves. 3-deep gload_lds pipeline with counted
// vmcnt(4) at raw s_barrier boundaries (T3/T4-lite); both-sides chunk swizzle
// chunk^=(row>>1)&3 on [128][32] LDS tiles (T2); setprio around MFMA (T5);
// XCD-contiguous block remap (T1). qcols/qscale: pre-scale Q cols (exp2 dom).
template <int STORE_BF16>
__global__ __launch_bounds__(256) void gemm_nt(
    const u16* __restrict__ A, const u16* __restrict__ BT,
    const float* __restrict__ bias, void* __restrict__ Cv,
    int M, int N, int K, int qcols, float qscale, int nbx)
{
    __shared__ __align__(16) u16 SM[24576];   // 3 sets x (A[128][32] | B[128][32])
    const int tid = threadIdx.x;
    const int w = tid >> 6, l = tid & 63;
    const int lr = l & 15, lh = l >> 4;
    const int wr = (w >> 1) * 64, wc = (w & 1) * 64;

    // XCD-contiguous remap (requires gridDim.x % 8 == 0)
    const int nwg = gridDim.x;
    const int swz = (blockIdx.x & 7) * (nwg >> 3) + (blockIdx.x >> 3);
    const int m0 = (swz / nbx) * 128;
    const int n0 = (swz % nbx) * 128;

    const int NT = K >> 5;

    // staging: 2 loads A + 2 loads B per thread per tile; LDS dest linear,
    // global source pre-swizzled (G21 both-sides discipline).
    const int f0 = tid, f1 = 256 + tid;
    const int r0 = f0 >> 2, r1 = f1 >> 2;
    const int cs0 = ((f0 & 3) ^ ((r0 >> 1) & 3)) * 8;
    const int cs1 = ((f1 & 3) ^ ((r1 >> 1) & 3)) * 8;
    const size_t arow0 = (size_t)(m0 + r0) * K, arow1 = (size_t)(m0 + r1) * K;
    const size_t brow0 = (size_t)(n0 + r0) * K, brow1 = (size_t)(n0 + r1) * K;

#define STAGE_TILE(t, set)                                                     \
    do {                                                                       \
        const int kk_ = (t) * 32;                                              \
        u16* dst_ = SM + (set) * 8192 + w * 512;                               \
        g2l16(A + arow0 + kk_ + cs0, dst_);                                    \
        g2l16(BT + brow0 + kk_ + cs0, dst_ + 4096);                            \
        g2l16(A + arow1 + kk_ + cs1, dst_ + 2048);                             \
        g2l16(BT + brow1 + kk_ + cs1, dst_ + 4096 + 2048);                     \
    } while (0)

    f32x4 acc[4][4];
#pragma unroll
    for (int m = 0; m < 4; ++m)
#pragma unroll
        for (int n = 0; n < 4; ++n) acc[m][n] = (f32x4)(0.0f);

    // prologue: tiles 0,1 in flight; wait tile0 (4 newest outstanding = tile1)
    STAGE_TILE(0, 0);
    STAGE_TILE(1, 1);
    asm volatile("s_waitcnt vmcnt(4) lgkmcnt(0)\n\ts_barrier" ::: "memory");

    const int csw = (lr >> 1) & 3;
    int s0 = 0, s2 = 2;
    for (int t = 0; t < NT; ++t) {
        if (t + 2 < NT) STAGE_TILE(t + 2, s2);

        const u16* As = SM + s0 * 8192;
        const u16* Bs = As + 4096;
        bf16x8 af[4], bfr[4];
#pragma unroll
        for (int m = 0; m < 4; ++m)
            af[m] = *(const bf16x8*)&As[(wr + m * 16 + lr) * 32 + ((lh ^ csw) << 3)];
#pragma unroll
        for (int n = 0; n < 4; ++n)
            bfr[n] = *(const bf16x8*)&Bs[(wc + n * 16 + lr) * 32 + ((lh ^ csw) << 3)];
        __builtin_amdgcn_s_setprio(1);
#pragma unroll
        for (int m = 0; m < 4; ++m)
#pragma unroll
            for (int n = 0; n < 4; ++n)
                acc[m][n] = MFMA16(af[m], bfr[n], acc[m][n], 0, 0, 0);
        __builtin_amdgcn_s_setprio(0);

        // boundary: next tile must be resident; keep newest stage in flight
        if (t + 2 < NT)
            asm volatile("s_waitcnt vmcnt(4) lgkmcnt(0)\n\ts_barrier" ::: "memory");
        else if (t + 1 < NT)
            asm volatile("s_waitcnt vmcnt(0) lgkmcnt(0)\n\ts_barrier" ::: "memory");

        s0 = (s0 == 2) ? 0 : s0 + 1;
        s2 = (s2 == 2) ? 0 : s2 + 1;
    }
#undef STAGE_TILE

#pragma unroll
    for (int m = 0; m < 4; ++m) {
        int row = m0 + wr + m * 16 + lh * 4;
#pragma unroll
        for (int n = 0; n < 4; ++n) {
            int col = n0 + wc + n * 16 + lr;
            float bs = bias[col];
            float sc = (col < qcols) ? qscale : 1.0f;
#pragma unroll
            for (int j = 0; j < 4; ++j) {
                float v = (acc[m][n][j] + bs) * sc;
                if (STORE_BF16)
                    ((u16*)Cv)[(size_t)(row + j) * N + col] = f32_to_bf16_bits(v);
                else
                    ((float*)Cv)[(size_t)(row + j) * N + col] = v;
            }
        }
    }
}

// ---------------- causal flash attention v7: 32x32 MFMA (unchanged) ----------------
__global__ __launch_bounds__(512, 2) void attn_kernel(
    const u16* __restrict__ qkv, u16* __restrict__ ctx)
{
    __shared__ __align__(16) u16 SM[32768];  // K 2x8KB | V 2x8KB | P 8x4KB

    const int bid = blockIdx.x;
    const int xcd = bid & 7, jj = bid >> 3;        // 32 blocks per XCD
    const int bh = xcd * 8 + (jj >> 2);            // 8 heads per XCD (4MB KV = L2)
    const int pr = jj & 3;                         // pair: qt = pr, then 7-pr
    const int b = bh >> 4, h = bh & 15;
    const size_t rowbase = (size_t)b * 2048;
    const int tid = threadIdx.x, w = tid >> 6, l = tid & 63;
    const int lq = l & 31, lk = l >> 5;            // q-col owner, k-half
    u16* const PL = SM + 16384 + w * 2048;         // [32][64] per wave, (q&7) key

    const int rstage = w * 8 + (l >> 3);
    const int cstage = l & 7;
    const int kchunk = cstage ^ (l >> 3);          // inverse-swizzle src (key=row&7)

    bf16x8 vreg;

#pragma unroll
    for (int pass = 0; pass < 2; ++pass) {
        const int qt = pass ? (7 - pr) : pr;
        const int q0 = qt * 256;
        const int nt = 4 * qt + 4;
        const int qbase = q0 + w * 32;

        const u16* qp = qkv + (rowbase + qbase + lq) * 3072 + h * 64 + lk * 8;
        bf16x8 qf[4];
#pragma unroll
        for (int j = 0; j < 4; ++j) qf[j] = *(const bf16x8*)(qp + j * 16);

        f32x16 ot[2];
#pragma unroll
        for (int dt = 0; dt < 2; ++dt) ot[dt] = (f32x16)(0.0f);
        float m_run = -3e38f, l_run = 0.0f;

        __syncthreads();
        g2l16(qkv + (rowbase + rstage) * 3072 + 1024 + h * 64 + kchunk * 8, SM + w * 512);
        vreg = *(const bf16x8*)(qkv + (rowbase + rstage) * 3072 + 2048 + h * 64 + cstage * 8);
        asm volatile("s_waitcnt vmcnt(0)" ::: "memory");
#pragma unroll
        for (int i = 0; i < 8; ++i) {
            const int d = cstage * 8 + i;
            SM[8192 + (((d * 64 + rstage) ^ (((i ^ cstage) & 7) << 3)))] = ((const u16*)&vreg)[i];
        }
        __syncthreads();

        for (int t = 0; t < nt; ++t) {
            const int c = t & 1;
            const int kb = t * 64;
            u16* const Kb = SM + (c ? 4096 : 0);
            u16* const Vb = SM + 8192 + (c ? 4096 : 0);

            if (t + 1 < nt) {
                const int kb2 = kb + 64;
                g2l16(qkv + (rowbase + kb2 + rstage) * 3072 + 1024 + h * 64 + kchunk * 8,
                      SM + (c ? 0 : 4096) + w * 512);
                vreg = *(const bf16x8*)(qkv + (rowbase + kb2 + rstage) * 3072 + 2048 + h * 64 + cstage * 8);
            }

            if (kb <= qbase + 31) {
                bf16x8 kf[2][4];
#pragma unroll
                for (int kt = 0; kt < 2; ++kt)
#pragma unroll
                    for (int j = 0; j < 4; ++j)
                        kf[kt][j] = *(const bf16x8*)&Kb[((kt * 32 + lq) * 64 + j * 16 + lk * 8) ^ ((lq & 7) << 3)];

                f32x16 sf[2];
                __builtin_amdgcn_s_setprio(1);
#pragma unroll
                for (int kt = 0; kt < 2; ++kt) {
                    f32x16 z = (f32x16)(0.0f);
#pragma unroll
                    for (int j = 0; j < 4; ++j) z = MFMA32(kf[kt][j], qf[j], z, 0, 0, 0);
                    sf[kt] = z;
                }
                __builtin_amdgcn_s_setprio(0);

                float mt = -3e38f;
                if (kb + 63 > qbase) {
                    const int qrow = qbase + lq;
#pragma unroll
                    for (int kt = 0; kt < 2; ++kt)
#pragma unroll
                        for (int r = 0; r < 16; ++r) {
                            const int key = kb + kt * 32 + (r & 3) + 8 * (r >> 2) + 4 * lk;
                            float v = sf[kt][r];
                            if (key > qrow) v = -3e38f;
                            sf[kt][r] = v;
                            mt = fmaxf(mt, v);
                        }
                } else {
#pragma unroll
                    for (int kt = 0; kt < 2; ++kt)
#pragma unroll
                        for (int r = 0; r < 16; ++r) mt = fmaxf(mt, sf[kt][r]);
                }
                mt = fmaxf(mt, __shfl_xor(mt, 32));

                const bool defer = __all(mt <= m_run + 16.0f);
                float mn = m_run;
                if (!defer) {
                    mn = fmaxf(m_run, mt);
                    const float alpha = EXP2F(m_run - mn);
                    m_run = mn;
                    l_run *= alpha;
#pragma unroll
                    for (int dt = 0; dt < 2; ++dt)
#pragma unroll
                        for (int r = 0; r < 16; ++r) ot[dt][r] *= alpha;
                }
                float rs = 0.0f;
#pragma unroll
                for (int kt = 0; kt < 2; ++kt)
#pragma unroll
                    for (int r = 0; r < 16; ++r) {
                        const float pp = EXP2F(sf[kt][r] - mn);
                        sf[kt][r] = pp;
                        rs += pp;
                    }
                rs += __shfl_xor(rs, 32);
                l_run += rs;

#pragma unroll
                for (int kt = 0; kt < 2; ++kt)
#pragma unroll
                    for (int rg = 0; rg < 4; ++rg) {
                        u16x4 pk;
#pragma unroll
                        for (int j2 = 0; j2 < 4; ++j2) pk[j2] = f32_to_bf16_fast(sf[kt][rg * 4 + j2]);
                        *(u16x4*)&PL[((lq * 64) + (kt * 32 + rg * 8 + lk * 4)) ^ ((lq & 7) << 3)] = pk;
                    }

                __builtin_amdgcn_s_setprio(1);
#pragma unroll
                for (int k0 = 0; k0 < 4; ++k0) {
                    const bf16x8 pb = *(const bf16x8*)&PL[((lq * 64) + (k0 * 16 + lk * 8)) ^ ((lq & 7) << 3)];
#pragma unroll
                    for (int dt = 0; dt < 2; ++dt) {
                        const int d = dt * 32 + lq;
                        const int vswz = ((d & 7) ^ (d >> 3)) & 7;
                        const bf16x8 vf = *(const bf16x8*)&Vb[((d * 64) + (k0 * 16 + lk * 8)) ^ (vswz << 3)];
                        ot[dt] = MFMA32(vf, pb, ot[dt], 0, 0, 0);
                    }
                }
                __builtin_amdgcn_s_setprio(0);
            }

            asm volatile("s_waitcnt vmcnt(0)" ::: "memory");
            if (t + 1 < nt) {
                u16* const Vn = SM + 8192 + (c ? 0 : 4096);
#pragma unroll
                for (int i = 0; i < 8; ++i) {
                    const int d = cstage * 8 + i;
                    Vn[((d * 64 + rstage) ^ (((i ^ cstage) & 7) << 3))] = ((const u16*)&vreg)[i];
                }
            }
            __syncthreads();
        }

        u16* const out_l = SM + w * 2176;   // [32][68] per wave
        const float inv = 1.0f / l_run;
#pragma unroll
        for (int dt = 0; dt < 2; ++dt)
#pragma unroll
            for (int r = 0; r < 16; ++r) {
                const int d = dt * 32 + (r & 3) + 8 * (r >> 2) + 4 * lk;
                out_l[lq * 68 + d] = f32_to_bf16_bits(ot[dt][r] * inv);
            }
#pragma unroll
        for (int rr = 0; rr < 4; ++rr) {
            const int row = rr * 8 + (l >> 3);
            const bf16x8 v = *(const bf16x8*)&out_l[row * 68 + (l & 7) * 8];
            *(bf16x8*)(ctx + (rowbase + qbase + row) * 1024 + h * 64 + (l & 7) * 8) = v;
        }
    }
}

extern "C" void kernel_launch(void* const* d_in, const int* in_sizes, int n_in,
                              void* d_out, int out_size, void* d_ws, size_t ws_size,
                              hipStream_t stream) {
    const float* x      = (const float*)d_in[0];
    const float* W_qkv  = (const float*)d_in[1];
    const float* b_qkv  = (const float*)d_in[2];
    const float* W_o    = (const float*)d_in[3];
    const float* b_o    = (const float*)d_in[4];
    float* out = (float*)d_out;

    const int M = 4 * 2048;     // 8192 rows
    const int C = 1024;
    u16* qkv   = (u16*)d_ws;                       // [8192][3072]
    u16* xb    = qkv   + (size_t)M * 3 * C;        // [8192][1024]
    u16* wqkvt = xb    + (size_t)M * C;            // [3072][1024]
    u16* ctx   = wqkvt + (size_t)3 * C * C;        // [8192][1024]
    u16* wot   = ctx   + (size_t)M * C;            // [1024][1024]

    const float SCQ = 0.125f * 1.44269504089f;     // 1/sqrt(64) * log2(e)

    cvt_bf16_kernel<<<(M * C) / (256 * 4), 256, 0, stream>>>(x, xb, M * C);
    cvt_t_kernel<<<dim3(3 * C / 64, C / 32), 256, 0, stream>>>(W_qkv, wqkvt, C, 3 * C);
    cvt_t_kernel<<<dim3(C / 64, C / 32), 256, 0, stream>>>(W_o, wot, C, C);

    // QKV projection: grid 24*64=1536 (%8==0), nbx=24
    gemm_nt<1><<<(3 * C / 128) * (M / 128), 256, 0, stream>>>(xb, wqkvt, b_qkv, qkv,
                                                              M, 3 * C, C, C, SCQ, 3 * C / 128);

    attn_kernel<<<256, 512, 0, stream>>>(qkv, ctx);

    // output projection: grid 8*64=512 (%8==0), nbx=8
    gemm_nt<0><<<(C / 128) * (M / 128), 256, 0, stream>>>(ctx, wot, b_o, out,
                                                          M, C, C, 0, 1.0f, C / 128);
}

// Round 13
// 169.097 us; speedup vs baseline: 1.3576x; 1.0391x over previous
//
#include <hip/hip_runtime.h>
#include <hip/hip_bf16.h>

typedef __attribute__((ext_vector_type(8))) __bf16 bf16x8;
typedef __attribute__((ext_vector_type(4))) float f32x4;
typedef __attribute__((ext_vector_type(16))) float f32x16;
typedef __attribute__((ext_vector_type(4))) unsigned short u16x4;
typedef __attribute__((ext_vector_type(8))) unsigned short u16x8;
typedef __attribute__((ext_vector_type(4))) unsigned int u32x4;
typedef unsigned short u16;

#define MFMA16 __builtin_amdgcn_mfma_f32_16x16x32_bf16
#define MFMA32 __builtin_amdgcn_mfma_f32_32x32x16_bf16

#if __has_builtin(__builtin_amdgcn_exp2f)
#define EXP2F __builtin_amdgcn_exp2f
#else
#define EXP2F(x) __expf((x) * 0.69314718056f)
#endif

__device__ inline u16 f32_to_bf16_bits(float f) {      // RNE (weights/outputs)
    unsigned u = __builtin_bit_cast(unsigned, f);
    unsigned r = u + 0x7FFFu + ((u >> 16) & 1u);
    return (u16)(r >> 16);
}

__device__ inline void g2l16(const void* g, void* l) {
    __builtin_amdgcn_global_load_lds(
        (const __attribute__((address_space(1))) unsigned int*)g,
        (__attribute__((address_space(3))) unsigned int*)l,
        16, 0, 0);
}

// lane i <-> i+32 reduce. NOTE: an earlier permlane32_swap version had an
// inline-asm register-aliasing bug ("+v"(b),"+v"(a) with b==a -> compiler
// assigns ONE VGPR -> in-place half swap, reduce returns partner value only).
// __shfl_xor is proven correct (R9/R10) and not on the critical path.
__device__ inline float red32_max(float x) { return fmaxf(x, __shfl_xor(x, 32)); }
__device__ inline float red32_sum(float x) { return x + __shfl_xor(x, 32); }

// ---------------- convert: f32 -> bf16 (vectorized) ----------------
__global__ void cvt_bf16_kernel(const float* __restrict__ in, u16* __restrict__ out, int n) {
    int i = (blockIdx.x * 256 + threadIdx.x) * 4;
    if (i >= n) return;
    f32x4 v = *(const f32x4*)&in[i];
    u16x4 r;
#pragma unroll
    for (int j = 0; j < 4; ++j) r[j] = f32_to_bf16_bits(v[j]);
    *(u16x4*)&out[i] = r;
}

// ---------------- transpose+convert: W[K][N] f32 -> WT[N][K] bf16 ----------------
__global__ __launch_bounds__(256) void cvt_t_kernel(const float* __restrict__ W,
                                                    u16* __restrict__ WT, int K, int N) {
    const int w = threadIdx.x >> 6, l = threadIdx.x & 63;
    const int n = blockIdx.x * 64 + l;
    const int k0 = blockIdx.y * 32 + w * 8;
    u16x8 r;
#pragma unroll
    for (int i = 0; i < 8; ++i)
        r[i] = f32_to_bf16_bits(W[(size_t)(k0 + i) * N + n]);
    *(u16x8*)&WT[(size_t)n * K + k0] = r;
}

// ---------------- GEMM v2: C[M][N] = A[M][K] * BT[N][K]^T + bias ----------------
// 128x128 tile, BK=32, 3-deep gload_lds pipeline, counted vmcnt(4) at raw
// s_barrier boundaries; both-sides chunk swizzle; setprio; XCD-contiguous remap.
template <int STORE_BF16>
__global__ __launch_bounds__(256) void gemm_nt(
    const u16* __restrict__ A, const u16* __restrict__ BT,
    const float* __restrict__ bias, void* __restrict__ Cv,
    int M, int N, int K, int qcols, float qscale, int nbx)
{
    __shared__ __align__(16) u16 SM[24576];   // 3 sets x (A[128][32] | B[128][32])
    const int tid = threadIdx.x;
    const int w = tid >> 6, l = tid & 63;
    const int lr = l & 15, lh = l >> 4;
    const int wr = (w >> 1) * 64, wc = (w & 1) * 64;

    const int nwg = gridDim.x;
    const int swz = (blockIdx.x & 7) * (nwg >> 3) + (blockIdx.x >> 3);
    const int m0 = (swz / nbx) * 128;
    const int n0 = (swz % nbx) * 128;

    const int NT = K >> 5;

    const int f0 = tid, f1 = 256 + tid;
    const int r0 = f0 >> 2, r1 = f1 >> 2;
    const int cs0 = ((f0 & 3) ^ ((r0 >> 1) & 3)) * 8;
    const int cs1 = ((f1 & 3) ^ ((r1 >> 1) & 3)) * 8;
    const size_t arow0 = (size_t)(m0 + r0) * K, arow1 = (size_t)(m0 + r1) * K;
    const size_t brow0 = (size_t)(n0 + r0) * K, brow1 = (size_t)(n0 + r1) * K;

#define STAGE_TILE(t, set)                                                     \
    do {                                                                       \
        const int kk_ = (t) * 32;                                              \
        u16* dst_ = SM + (set) * 8192 + w * 512;                               \
        g2l16(A + arow0 + kk_ + cs0, dst_);                                    \
        g2l16(BT + brow0 + kk_ + cs0, dst_ + 4096);                            \
        g2l16(A + arow1 + kk_ + cs1, dst_ + 2048);                             \
        g2l16(BT + brow1 + kk_ + cs1, dst_ + 4096 + 2048);                     \
    } while (0)

    f32x4 acc[4][4];
#pragma unroll
    for (int m = 0; m < 4; ++m)
#pragma unroll
        for (int n = 0; n < 4; ++n) acc[m][n] = (f32x4)(0.0f);

    STAGE_TILE(0, 0);
    STAGE_TILE(1, 1);
    asm volatile("s_waitcnt vmcnt(4) lgkmcnt(0)\n\ts_barrier" ::: "memory");

    const int csw = (lr >> 1) & 3;
    int s0 = 0, s2 = 2;
    for (int t = 0; t < NT; ++t) {
        if (t + 2 < NT) STAGE_TILE(t + 2, s2);

        const u16* As = SM + s0 * 8192;
        const u16* Bs = As + 4096;
        bf16x8 af[4], bfr[4];
#pragma unroll
        for (int m = 0; m < 4; ++m)
            af[m] = *(const bf16x8*)&As[(wr + m * 16 + lr) * 32 + ((lh ^ csw) << 3)];
#pragma unroll
        for (int n = 0; n < 4; ++n)
            bfr[n] = *(const bf16x8*)&Bs[(wc + n * 16 + lr) * 32 + ((lh ^ csw) << 3)];
        __builtin_amdgcn_s_setprio(1);
#pragma unroll
        for (int m = 0; m < 4; ++m)
#pragma unroll
            for (int n = 0; n < 4; ++n)
                acc[m][n] = MFMA16(af[m], bfr[n], acc[m][n], 0, 0, 0);
        __builtin_amdgcn_s_setprio(0);

        if (t + 2 < NT)
            asm volatile("s_waitcnt vmcnt(4) lgkmcnt(0)\n\ts_barrier" ::: "memory");
        else if (t + 1 < NT)
            asm volatile("s_waitcnt vmcnt(0) lgkmcnt(0)\n\ts_barrier" ::: "memory");

        s0 = (s0 == 2) ? 0 : s0 + 1;
        s2 = (s2 == 2) ? 0 : s2 + 1;
    }
#undef STAGE_TILE

#pragma unroll
    for (int m = 0; m < 4; ++m) {
        int row = m0 + wr + m * 16 + lh * 4;
#pragma unroll
        for (int n = 0; n < 4; ++n) {
            int col = n0 + wc + n * 16 + lr;
            float bs = bias[col];
            float sc = (col < qcols) ? qscale : 1.0f;
#pragma unroll
            for (int j = 0; j < 4; ++j) {
                float v = (acc[m][n][j] + bs) * sc;
                if (STORE_BF16)
                    ((u16*)Cv)[(size_t)(row + j) * N + col] = f32_to_bf16_bits(v);
                else
                    ((float*)Cv)[(size_t)(row + j) * N + col] = v;
            }
        }
    }
}

// ---------------- causal flash attention v8.2: 32x32 MFMA + in-register P ----------------
// T12: P stays in registers; PV B-frags via cvt_pk_bf16_f32 + permlane32_swap
// (ISA: vdst upper 32 lanes <-> vsrc lower 32 lanes, i.e. A'=[A.lo,B.lo],
// B'=[A.hi,B.hi]; pairing verified against the R10 LDS path's key mapping).
// Softmax reduces via __shfl_xor(32) (proven).
__global__ __launch_bounds__(512, 2) void attn_kernel(
    const u16* __restrict__ qkv, u16* __restrict__ ctx)
{
    __shared__ __align__(16) u16 SM[17408];  // K 2x8KB | V 2x8KB (| epilogue)

    const int bid = blockIdx.x;
    const int xcd = bid & 7, jj = bid >> 3;        // 32 blocks per XCD
    const int bh = xcd * 8 + (jj >> 2);            // 8 heads per XCD (4MB KV = L2)
    const int pr = jj & 3;                         // pair: qt = pr, then 7-pr
    const int b = bh >> 4, h = bh & 15;
    const size_t rowbase = (size_t)b * 2048;
    const int tid = threadIdx.x, w = tid >> 6, l = tid & 63;
    const int lq = l & 31, lk = l >> 5;            // q-col owner, k-half

    const int rstage = w * 8 + (l >> 3);
    const int cstage = l & 7;
    const int kchunk = cstage ^ (l >> 3);          // inverse-swizzle src (key=row&7)

    bf16x8 vreg;

#pragma unroll
    for (int pass = 0; pass < 2; ++pass) {
        const int qt = pass ? (7 - pr) : pr;
        const int q0 = qt * 256;
        const int nt = 4 * qt + 4;
        const int qbase = q0 + w * 32;

        const u16* qp = qkv + (rowbase + qbase + lq) * 3072 + h * 64 + lk * 8;
        bf16x8 qf[4];
#pragma unroll
        for (int j = 0; j < 4; ++j) qf[j] = *(const bf16x8*)(qp + j * 16);

        f32x16 ot[2];
#pragma unroll
        for (int dt = 0; dt < 2; ++dt) ot[dt] = (f32x16)(0.0f);
        float m_run = -3e38f, l_run = 0.0f;

        __syncthreads();
        g2l16(qkv + (rowbase + rstage) * 3072 + 1024 + h * 64 + kchunk * 8, SM + w * 512);
        vreg = *(const bf16x8*)(qkv + (rowbase + rstage) * 3072 + 2048 + h * 64 + cstage * 8);
        asm volatile("s_waitcnt vmcnt(0)" ::: "memory");
#pragma unroll
        for (int i = 0; i < 8; ++i) {
            const int d = cstage * 8 + i;
            SM[8192 + (((d * 64 + rstage) ^ (((i ^ cstage) & 7) << 3)))] = ((const u16*)&vreg)[i];
        }
        __syncthreads();

        for (int t = 0; t < nt; ++t) {
            const int c = t & 1;
            const int kb = t * 64;
            u16* const Kb = SM + (c ? 4096 : 0);
            u16* const Vb = SM + 8192 + (c ? 4096 : 0);

            if (t + 1 < nt) {   // issue next-tile staging first
                const int kb2 = kb + 64;
                g2l16(qkv + (rowbase + kb2 + rstage) * 3072 + 1024 + h * 64 + kchunk * 8,
                      SM + (c ? 0 : 4096) + w * 512);
                vreg = *(const bf16x8*)(qkv + (rowbase + kb2 + rstage) * 3072 + 2048 + h * 64 + cstage * 8);
            }

            if (kb <= qbase + 31) {   // strip visible
                bf16x8 kf[2][4];
#pragma unroll
                for (int kt = 0; kt < 2; ++kt)
#pragma unroll
                    for (int j = 0; j < 4; ++j)
                        kf[kt][j] = *(const bf16x8*)&Kb[((kt * 32 + lq) * 64 + j * 16 + lk * 8) ^ ((lq & 7) << 3)];

                f32x16 sf[2];
                __builtin_amdgcn_s_setprio(1);
#pragma unroll
                for (int kt = 0; kt < 2; ++kt) {
                    f32x16 z = (f32x16)(0.0f);
#pragma unroll
                    for (int j = 0; j < 4; ++j) z = MFMA32(kf[kt][j], qf[j], z, 0, 0, 0);
                    sf[kt] = z;
                }
                __builtin_amdgcn_s_setprio(0);

                float mt = -3e38f;
                if (kb + 63 > qbase) {          // diagonal tile: causal mask
                    const int qrow = qbase + lq;
#pragma unroll
                    for (int kt = 0; kt < 2; ++kt)
#pragma unroll
                        for (int r = 0; r < 16; ++r) {
                            const int key = kb + kt * 32 + (r & 3) + 8 * (r >> 2) + 4 * lk;
                            float v = sf[kt][r];
                            if (key > qrow) v = -3e38f;
                            sf[kt][r] = v;
                            mt = fmaxf(mt, v);
                        }
                } else {
#pragma unroll
                    for (int kt = 0; kt < 2; ++kt)
#pragma unroll
                        for (int r = 0; r < 16; ++r) mt = fmaxf(mt, sf[kt][r]);
                }
                mt = red32_max(mt);             // q-col split across lane/lane+32

                const bool defer = __all(mt <= m_run + 16.0f);
                float mn = m_run;
                if (!defer) {
                    mn = fmaxf(m_run, mt);
                    const float alpha = EXP2F(m_run - mn);
                    m_run = mn;
                    l_run *= alpha;
#pragma unroll
                    for (int dt = 0; dt < 2; ++dt)
#pragma unroll
                        for (int r = 0; r < 16; ++r) ot[dt][r] *= alpha;
                }
                float rs = 0.0f;
#pragma unroll
                for (int kt = 0; kt < 2; ++kt)
#pragma unroll
                    for (int r = 0; r < 16; ++r) {
                        const float pp = EXP2F(sf[kt][r] - mn);
                        sf[kt][r] = pp;
                        rs += pp;
                    }
                l_run += red32_sum(rs);

                // T12: P -> bf16 dwords in-register; pc[kt][rg] = keys 32kt+8rg+4lk+{0..3}
                unsigned pc[2][4][2];
#pragma unroll
                for (int kt = 0; kt < 2; ++kt)
#pragma unroll
                    for (int rg = 0; rg < 4; ++rg) {
                        unsigned d0, d1;
                        asm("v_cvt_pk_bf16_f32 %0, %1, %2"
                            : "=v"(d0) : "v"((float)sf[kt][rg * 4 + 0]), "v"((float)sf[kt][rg * 4 + 1]));
                        asm("v_cvt_pk_bf16_f32 %0, %1, %2"
                            : "=v"(d1) : "v"((float)sf[kt][rg * 4 + 2]), "v"((float)sf[kt][rg * 4 + 3]));
                        pc[kt][rg][0] = d0;
                        pc[kt][rg][1] = d1;
                    }

                // PV: O^T[d][q] += V^T * P.  swap(A=even-rg, B=odd-rg):
                // A' = [A.lo,B.lo] (elems 0-3), B' = [A.hi,B.hi] (elems 4-7).
                __builtin_amdgcn_s_setprio(1);
#pragma unroll
                for (int kt = 0; kt < 2; ++kt)
#pragma unroll
                    for (int hh = 0; hh < 2; ++hh) {
                        unsigned a0 = pc[kt][2 * hh][0], a1 = pc[kt][2 * hh][1];
                        unsigned b0 = pc[kt][2 * hh + 1][0], b1 = pc[kt][2 * hh + 1][1];
                        asm("v_permlane32_swap_b32 %0, %1" : "+v"(a0), "+v"(b0));
                        asm("v_permlane32_swap_b32 %0, %1" : "+v"(a1), "+v"(b1));
                        u32x4 wv = {a0, a1, b0, b1};
                        const bf16x8 pb = __builtin_bit_cast(bf16x8, wv);
                        const int k0 = 2 * kt + hh;
#pragma unroll
                        for (int dt = 0; dt < 2; ++dt) {
                            const int d = dt * 32 + lq;
                            const int vswz = ((d & 7) ^ (d >> 3)) & 7;
                            const bf16x8 vf = *(const bf16x8*)&Vb[((d * 64) + (k0 * 16 + lk * 8)) ^ (vswz << 3)];
                            ot[dt] = MFMA32(vf, pb, ot[dt], 0, 0, 0);
                        }
                    }
                __builtin_amdgcn_s_setprio(0);
            }

            asm volatile("s_waitcnt vmcnt(0)" ::: "memory");
            if (t + 1 < nt) {
                u16* const Vn = SM + 8192 + (c ? 0 : 4096);
#pragma unroll
                for (int i = 0; i < 8; ++i) {
                    const int d = cstage * 8 + i;
                    Vn[((d * 64 + rstage) ^ (((i ^ cstage) & 7) << 3))] = ((const u16*)&vreg)[i];
                }
            }
            __syncthreads();   // single barrier per tile-step
        }

        // ---- epilogue: O^T -> LDS transpose -> coalesced bf16 stores ----
        u16* const out_l = SM + w * 2176;   // [32][68] per wave (private region)
        const float inv = 1.0f / l_run;
#pragma unroll
        for (int dt = 0; dt < 2; ++dt)
#pragma unroll
            for (int r = 0; r < 16; ++r) {
                const int d = dt * 32 + (r & 3) + 8 * (r >> 2) + 4 * lk;
                out_l[lq * 68 + d] = f32_to_bf16_bits(ot[dt][r] * inv);
            }
#pragma unroll
        for (int rr = 0; rr < 4; ++rr) {
            const int row = rr * 8 + (l >> 3);
            const bf16x8 v = *(const bf16x8*)&out_l[row * 68 + (l & 7) * 8];
            *(bf16x8*)(ctx + (rowbase + qbase + row) * 1024 + h * 64 + (l & 7) * 8) = v;
        }
    }
}

extern "C" void kernel_launch(void* const* d_in, const int* in_sizes, int n_in,
                              void* d_out, int out_size, void* d_ws, size_t ws_size,
                              hipStream_t stream) {
    const float* x      = (const float*)d_in[0];
    const float* W_qkv  = (const float*)d_in[1];
    const float* b_qkv  = (const float*)d_in[2];
    const float* W_o    = (const float*)d_in[3];
    const float* b_o    = (const float*)d_in[4];
    float* out = (float*)d_out;

    const int M = 4 * 2048;     // 8192 rows
    const int C = 1024;
    u16* qkv   = (u16*)d_ws;                       // [8192][3072]
    u16* xb    = qkv   + (size_t)M * 3 * C;        // [8192][1024]
    u16* wqkvt = xb    + (size_t)M * C;            // [3072][1024]
    u16* ctx   = wqkvt + (size_t)3 * C * C;        // [8192][1024]
    u16* wot   = ctx   + (size_t)M * C;            // [1024][1024]

    const float SCQ = 0.125f * 1.44269504089f;     // 1/sqrt(64) * log2(e)

    cvt_bf16_kernel<<<(M * C) / (256 * 4), 256, 0, stream>>>(x, xb, M * C);
    cvt_t_kernel<<<dim3(3 * C / 64, C / 32), 256, 0, stream>>>(W_qkv, wqkvt, C, 3 * C);
    cvt_t_kernel<<<dim3(C / 64, C / 32), 256, 0, stream>>>(W_o, wot, C, C);

    gemm_nt<1><<<(3 * C / 128) * (M / 128), 256, 0, stream>>>(xb, wqkvt, b_qkv, qkv,
                                                              M, 3 * C, C, C, SCQ, 3 * C / 128);

    attn_kernel<<<256, 512, 0, stream>>>(qkv, ctx);

    gemm_nt<0><<<(C / 128) * (M / 128), 256, 0, stream>>>(ctx, wot, b_o, out,
                                                          M, C, C, 0, 1.0f, C / 128);
}